// Round 1
// baseline (191.240 us; speedup 1.0000x reference)
//
#include <hip/hip_runtime.h>
#include <math.h>

#define D_MODEL 1024
#define NUM_EXPERTS 8
#define TOP_K 2
#define TOKENS_PER_WAVE 8
#define WAVES_PER_BLOCK 4
#define TOKENS_PER_BLOCK (TOKENS_PER_WAVE * WAVES_PER_BLOCK)  // 32

typedef float f4 __attribute__((ext_vector_type(4)));

// One DPP-permute + add. CTRL is a compile-time DPP control code.
template<int CTRL>
__device__ __forceinline__ float dpp_add(float v) {
    int s = __builtin_amdgcn_update_dpp(0, __builtin_bit_cast(int, v),
                                        CTRL, 0xF, 0xF, true);
    return v + __builtin_bit_cast(float, s);
}

// Full 64-lane sum. XOR-butterfly-style pairings so every lane computes the
// sum with identical operand grouping -> bit-identical result in all lanes
// (required: lanes 0-1 store weights, lane 2 stores indices; they must agree
// on top-k even at near-ties).
//   xor1  : quad_perm(1,0,3,2) = 0xB1          (VALU/DPP)
//   xor2  : quad_perm(2,3,0,1) = 0x4E          (VALU/DPP)
//   xor7  : row_half_mirror    = 0x141         (VALU/DPP)  combines quads
//   xor15 : row_mirror         = 0x140         (VALU/DPP)  combines octets
//   xor16 : ds_swizzle 0x401F                  (LDS pipe, 1 op)
//   xor32 : permlane32_swap                    (VALU)
__device__ __forceinline__ float wave_sum64(float v) {
    v = dpp_add<0xB1>(v);
    v = dpp_add<0x4E>(v);
    v = dpp_add<0x141>(v);
    v = dpp_add<0x140>(v);
    int t = __builtin_amdgcn_ds_swizzle(__builtin_bit_cast(int, v), 0x401F);
    v += __builtin_bit_cast(float, t);
#if __has_builtin(__builtin_amdgcn_permlane32_swap)
    {
        unsigned a = __builtin_bit_cast(unsigned, v);
        auto p = __builtin_amdgcn_permlane32_swap(a, a, false, false);
        v = __builtin_bit_cast(float, (unsigned)p[0]) +
            __builtin_bit_cast(float, (unsigned)p[1]);
    }
#else
    v += __shfl_xor(v, 32, 64);
#endif
    return v;
}

__device__ __forceinline__ float dot4(f4 a, f4 b) {
    return a.x * b.x + a.y * b.y + a.z * b.z + a.w * b.w;
}

// Layout: one wave processes TOKENS_PER_WAVE consecutive tokens, one at a
// time, 64 lanes cooperating per token. Lane l owns d-slice (i*64+l)*4..+3
// for i=0..3. W lives entirely in VGPRs (8e x 4i float4 = 128 VGPR/lane) --
// zero LDS in the inner loop (previous version moved 32KB of W through the
// LDS return path per token = ~20.5us/CU on the LDS pipe, tied with HBM).
// x loads: 4 x 1KB fully-contiguous wave loads per token, nontemporal.
__global__ __launch_bounds__(256) void gating_kernel(
    const float* __restrict__ x, const float* __restrict__ W,
    const float* __restrict__ b, float* __restrict__ out_w,
    float* __restrict__ out_idx, int n_tokens)
{
    const int wave = threadIdx.x >> 6;
    const int lane = threadIdx.x & 63;
    const int wid = blockIdx.x * WAVES_PER_BLOCK + wave;
    const int token0 = wid * TOKENS_PER_WAVE;
    if (token0 >= n_tokens) return;
    const int nt = (n_tokens - token0 < TOKENS_PER_WAVE) ? (n_tokens - token0)
                                                         : TOKENS_PER_WAVE;

    // W -> registers: Wr[e][i] = W[e][(i*64+lane)*4 .. +3]. Cached reads (L2-hot
    // after first block); do NOT use nontemporal here.
    f4 Wr[NUM_EXPERTS][4];
    {
        const f4* Wg = (const f4*)W + lane;
#pragma unroll
        for (int e = 0; e < NUM_EXPERTS; ++e)
#pragma unroll
            for (int i = 0; i < 4; ++i)
                Wr[e][i] = Wg[e * 256 + i * 64];
    }
    const f4 blo = ((const f4*)b)[0];
    const f4 bhi = ((const f4*)b)[1];
    const float bb[NUM_EXPERTS] = {blo.x, blo.y, blo.z, blo.w,
                                   bhi.x, bhi.y, bhi.z, bhi.w};

    const f4* xw = (const f4*)x + (size_t)token0 * (D_MODEL / 4) + lane;

    // Software pipeline: prefetch token t+1's row while computing token t.
    f4 xs[2][4];
#pragma unroll
    for (int i = 0; i < 4; ++i)
        xs[0][i] = __builtin_nontemporal_load(xw + i * 64);

#pragma unroll
    for (int t = 0; t < TOKENS_PER_WAVE; ++t) {
        const int cur = t & 1;
        const int nxt = cur ^ 1;
        if (t + 1 < nt) {
#pragma unroll
            for (int i = 0; i < 4; ++i)
                xs[nxt][i] =
                    __builtin_nontemporal_load(xw + (t + 1) * 256 + i * 64);
        }
        if (t >= nt) break;  // wave-uniform

        // Per-lane partial dot (16 elements per expert), then 64-lane sum.
        float acc[NUM_EXPERTS];
#pragma unroll
        for (int e = 0; e < NUM_EXPERTS; ++e) {
            float s = dot4(xs[cur][0], Wr[e][0]) + dot4(xs[cur][1], Wr[e][1]) +
                      dot4(xs[cur][2], Wr[e][2]) + dot4(xs[cur][3], Wr[e][3]);
            acc[e] = wave_sum64(s) + bb[e];
        }

        // All 64 lanes now hold bit-identical logits. Top-2 + softmax.
        float v0 = -INFINITY, v1 = -INFINITY;
        int i0 = 0, i1 = 0;
#pragma unroll
        for (int e = 0; e < NUM_EXPERTS; ++e) {
            float v = acc[e];
            // strict > keeps lowest index on ties, matching jax.lax.top_k
            if (v > v0) { v1 = v0; i1 = i0; v0 = v; i0 = e; }
            else if (v > v1) { v1 = v; i1 = e; }
        }
        const float e1 = expf(v1 - v0);
        const float w0 = 1.f / (1.f + e1);
        const float w1 = e1 * w0;

        const size_t token = (size_t)(token0 + t);
        if (lane < 2) {
            const int base = lane * 4;
            f4 v4;
            v4.x = (base + 0 == i0) ? w0 : ((base + 0 == i1) ? w1 : 0.f);
            v4.y = (base + 1 == i0) ? w0 : ((base + 1 == i1) ? w1 : 0.f);
            v4.z = (base + 2 == i0) ? w0 : ((base + 2 == i1) ? w1 : 0.f);
            v4.w = (base + 3 == i0) ? w0 : ((base + 3 == i1) ? w1 : 0.f);
            ((f4*)(out_w + token * NUM_EXPERTS))[lane] = v4;
        } else if (lane == 2) {
            *(float2*)(out_idx + token * TOP_K) =
                make_float2((float)i0, (float)i1);
        }
    }
}

extern "C" void kernel_launch(void* const* d_in, const int* in_sizes, int n_in,
                              void* d_out, int out_size, void* d_ws, size_t ws_size,
                              hipStream_t stream) {
    const float* x = (const float*)d_in[0];
    const float* W = (const float*)d_in[1];
    const float* b = (const float*)d_in[2];
    float* out = (float*)d_out;

    const int n_tokens = in_sizes[0] / D_MODEL;              // 32768
    float* out_w   = out;                                    // [n_tokens, 8]
    float* out_idx = out + (size_t)n_tokens * NUM_EXPERTS;   // [n_tokens, 2] as float

    const int grid = (n_tokens + TOKENS_PER_BLOCK - 1) / TOKENS_PER_BLOCK;  // 1024
    gating_kernel<<<grid, 256, 0, stream>>>(x, W, b, out_w, out_idx, n_tokens);
}